// Round 10
// baseline (569.796 us; speedup 1.0000x reference)
//
#include <hip/hip_runtime.h>
#include <hip/hip_fp16.h>
#include <hip/hip_cooperative_groups.h>

namespace cg = cooperative_groups;

#define B_DIM 64

__device__ __forceinline__ float fast_rcp(float x) {
#if __has_builtin(__builtin_amdgcn_rcpf)
    return __builtin_amdgcn_rcpf(x);
#else
    return 1.0f / x;
#endif
}

__device__ __forceinline__ float wave_sum(float x) {
    #pragma unroll
    for (int off = 1; off < 64; off <<= 1) x += __shfl_xor(x, off);
    return x;
}

// ---- value-only fp16 pack/unpack: NO address-taking, NO type-punned ptrs ----
__device__ __forceinline__ unsigned int pack2f(float a, float b) {
    const __half2 h = __floats2half2_rn(a, b);
    return __builtin_bit_cast(unsigned int, h);
}
__device__ __forceinline__ float2 unpack2f(unsigned int u) {
    return __half22float2(__builtin_bit_cast(__half2, u));
}

// One row's 16 cols of E, packed fp16 in 8 named uints (8 VGPRs).
struct Row { unsigned int r0, r1, r2, r3, r4, r5, r6, r7; };

#define REP16(M) M(0) M(1) M(2) M(3) M(4) M(5) M(6) M(7) \
                 M(8) M(9) M(10) M(11) M(12) M(13) M(14) M(15)

// Load+exp+pack one row; returns this lane's 16-col partial sum.
// Cols 0..511 always valid (nc >= 512); 512.. guarded; invalid -> 0.
__device__ __forceinline__ float load_row(
    const float* __restrict__ srow, const int c4, const int nc,
    const bool valid, Row& R)
{
    float e0=0.f,e1=0.f,e2=0.f,e3=0.f,e4=0.f,e5=0.f,e6=0.f,e7=0.f;
    float e8=0.f,e9=0.f,e10=0.f,e11=0.f,e12=0.f,e13=0.f,e14=0.f,e15=0.f;
    if (valid) {
        const float4 x0 = *reinterpret_cast<const float4*>(srow + c4);
        const float4 x1 = *reinterpret_cast<const float4*>(srow + 256 + c4);
        e0 = __expf(x0.x); e1 = __expf(x0.y); e2 = __expf(x0.z); e3 = __expf(x0.w);
        e4 = __expf(x1.x); e5 = __expf(x1.y); e6 = __expf(x1.z); e7 = __expf(x1.w);
        const int c2 = 512 + c4;
        if (c2 < nc) {
            const float4 x2 = *reinterpret_cast<const float4*>(srow + c2);
            e8  = __expf(x2.x);
            e9  = (c2 + 1 < nc) ? __expf(x2.y) : 0.f;
            e10 = (c2 + 2 < nc) ? __expf(x2.z) : 0.f;
            e11 = (c2 + 3 < nc) ? __expf(x2.w) : 0.f;
        }
        const int c3 = 768 + c4;
        if (c3 < nc) {
            const float4 x3 = *reinterpret_cast<const float4*>(srow + c3);
            e12 = __expf(x3.x);
            e13 = (c3 + 1 < nc) ? __expf(x3.y) : 0.f;
            e14 = (c3 + 2 < nc) ? __expf(x3.z) : 0.f;
            e15 = (c3 + 3 < nc) ? __expf(x3.w) : 0.f;
        }
    }
    R.r0 = pack2f(e0, e1);   R.r1 = pack2f(e2, e3);
    R.r2 = pack2f(e4, e5);   R.r3 = pack2f(e6, e7);
    R.r4 = pack2f(e8, e9);   R.r5 = pack2f(e10, e11);
    R.r6 = pack2f(e12, e13); R.r7 = pack2f(e14, e15);
    return (((e0 + e1) + (e2 + e3)) + ((e4 + e5) + (e6 + e7)))
         + (((e8 + e9) + (e10 + e11)) + ((e12 + e13) + (e14 + e15)));
}

__device__ __forceinline__ float row_dot(
    const Row& R, const float4 wv0, const float4 wv1,
    const float4 wv2, const float4 wv3)
{
    float2 f; float a0, a1;
    f = unpack2f(R.r0); a0 = f.x * wv0.x;          a1 = f.y * wv0.y;
    f = unpack2f(R.r1); a0 = fmaf(f.x, wv0.z, a0); a1 = fmaf(f.y, wv0.w, a1);
    f = unpack2f(R.r2); a0 = fmaf(f.x, wv1.x, a0); a1 = fmaf(f.y, wv1.y, a1);
    f = unpack2f(R.r3); a0 = fmaf(f.x, wv1.z, a0); a1 = fmaf(f.y, wv1.w, a1);
    f = unpack2f(R.r4); a0 = fmaf(f.x, wv2.x, a0); a1 = fmaf(f.y, wv2.y, a1);
    f = unpack2f(R.r5); a0 = fmaf(f.x, wv2.z, a0); a1 = fmaf(f.y, wv2.w, a1);
    f = unpack2f(R.r6); a0 = fmaf(f.x, wv3.x, a0); a1 = fmaf(f.y, wv3.y, a1);
    f = unpack2f(R.r7); a0 = fmaf(f.x, wv3.z, a0); a1 = fmaf(f.y, wv3.w, a1);
    return a0 + a1;
}

__device__ __forceinline__ void col_acc(
    const Row& R, const float av,
    float4& p0, float4& p1, float4& p2, float4& p3)
{
    float2 f;
    f = unpack2f(R.r0); p0.x = fmaf(f.x, av, p0.x); p0.y = fmaf(f.y, av, p0.y);
    f = unpack2f(R.r1); p0.z = fmaf(f.x, av, p0.z); p0.w = fmaf(f.y, av, p0.w);
    f = unpack2f(R.r2); p1.x = fmaf(f.x, av, p1.x); p1.y = fmaf(f.y, av, p1.y);
    f = unpack2f(R.r3); p1.z = fmaf(f.x, av, p1.z); p1.w = fmaf(f.y, av, p1.w);
    f = unpack2f(R.r4); p2.x = fmaf(f.x, av, p2.x); p2.y = fmaf(f.y, av, p2.y);
    f = unpack2f(R.r5); p2.z = fmaf(f.x, av, p2.z); p2.w = fmaf(f.y, av, p2.w);
    f = unpack2f(R.r6); p3.x = fmaf(f.x, av, p3.x); p3.y = fmaf(f.y, av, p3.y);
    f = unpack2f(R.r7); p3.z = fmaf(f.x, av, p3.z); p3.w = fmaf(f.y, av, p3.w);
}

__device__ __forceinline__ void load_wv(
    const float* __restrict__ csb, const int c4, const int nc,
    float4& wv0, float4& wv1, float4& wv2, float4& wv3)
{
    const float4 v0 = *reinterpret_cast<const float4*>(csb + c4);
    wv0 = make_float4(fast_rcp(v0.x), fast_rcp(v0.y),
                      fast_rcp(v0.z), fast_rcp(v0.w));
    const float4 v1 = *reinterpret_cast<const float4*>(csb + 256 + c4);
    wv1 = make_float4(fast_rcp(v1.x), fast_rcp(v1.y),
                      fast_rcp(v1.z), fast_rcp(v1.w));
    const int c2 = 512 + c4;
    if (c2 < nc) {
        const float4 v2 = *reinterpret_cast<const float4*>(csb + c2);
        wv2.x = fast_rcp(v2.x);
        wv2.y = (c2 + 1 < nc) ? fast_rcp(v2.y) : 0.f;
        wv2.z = (c2 + 2 < nc) ? fast_rcp(v2.z) : 0.f;
        wv2.w = (c2 + 3 < nc) ? fast_rcp(v2.w) : 0.f;
    } else { wv2 = make_float4(0.f, 0.f, 0.f, 0.f); }
    const int c3 = 768 + c4;
    if (c3 < nc) {
        const float4 v3 = *reinterpret_cast<const float4*>(csb + c3);
        wv3.x = fast_rcp(v3.x);
        wv3.y = (c3 + 1 < nc) ? fast_rcp(v3.y) : 0.f;
        wv3.z = (c3 + 2 < nc) ? fast_rcp(v3.z) : 0.f;
        wv3.w = (c3 + 3 < nc) ? fast_rcp(v3.w) : 0.f;
    } else { wv3 = make_float4(0.f, 0.f, 0.f, 0.f); }
}

__device__ __forceinline__ void out_row(
    const Row& R, const float av, const float4 wv0, const float4 wv1,
    const float4 wv2, const float4 wv3, float* __restrict__ orow, const int c4)
{
    float2 fa, fb;
    fa = unpack2f(R.r0); fb = unpack2f(R.r1);
    *reinterpret_cast<float4*>(orow + c4) =
        make_float4(fa.x*av*wv0.x, fa.y*av*wv0.y, fb.x*av*wv0.z, fb.y*av*wv0.w);
    fa = unpack2f(R.r2); fb = unpack2f(R.r3);
    *reinterpret_cast<float4*>(orow + 256 + c4) =
        make_float4(fa.x*av*wv1.x, fa.y*av*wv1.y, fb.x*av*wv1.z, fb.y*av*wv1.w);
    fa = unpack2f(R.r4); fb = unpack2f(R.r5);
    *reinterpret_cast<float4*>(orow + 512 + c4) =
        make_float4(fa.x*av*wv2.x, fa.y*av*wv2.y, fb.x*av*wv2.z, fb.y*av*wv2.w);
    fa = unpack2f(R.r6); fb = unpack2f(R.r7);
    *reinterpret_cast<float4*>(orow + 768 + c4) =
        make_float4(fa.x*av*wv3.x, fa.y*av*wv3.y, fb.x*av*wv3.z, fb.y*av*wv3.w);
}

// ================= cooperative single-kernel path =================
// grid 512 x 256, __launch_bounds__(256,2): 2 waves/SIMD -> VGPR cap 256,
// 2 blocks/CU co-resident. Block g: b = g>>3, half = g&7 (rows half*64..+63).
// Wave w: rows rbase = half*64 + w*16 + k (k=0..15). Lane l: cols
// {j*256 + 4l..+3}. E = 16 named Row structs (128 VGPRs packed fp16).
// 5 epochs {row-step; col partials -> LDS[4][1024] -> atomics} + grid.sync;
// cs0/1/2 rotate, zeroed one epoch ahead. Output straight from registers.

__global__ __launch_bounds__(256, 2) void sinkhorn_coop(
    const float* __restrict__ s, const int* __restrict__ nrows,
    const int* __restrict__ ncols, float* __restrict__ cs0,
    float* __restrict__ cs1, float* __restrict__ cs2,
    float* __restrict__ out)
{
    cg::grid_group grid = cg::this_grid();
    __shared__ float cls[4 * 1024];   // 16 KiB

    const int g = blockIdx.x;
    const int b = g >> 3;
    const int half = g & 7;
    const int t = threadIdx.x;
    const int w = t >> 6;
    const int l = t & 63;
    const int c4 = l << 2;
    const int nr = nrows[b];
    const int nc = ncols[b];
    const int rbase = (half << 6) + (w << 4);

#define DECLK(k) Row R##k; float aR##k;
    REP16(DECLK)
#undef DECLK

    // zero cs1 (epoch-1 target); cs0 pre-zeroed by host memset.
    if (t < 128) cs1[(b << 10) + (half << 7) + t] = 0.f;

    // ---- epoch 0 row step: load s, exp, pack, row sums (weights = 1) ----
    {
        const float* __restrict__ sb = s + ((size_t)b << 20);
#define LOADK(k) { \
        const int r_ = rbase + k; \
        float sum_ = load_row(sb + ((size_t)r_ << 10), c4, nc, r_ < nr, R##k); \
        sum_ = wave_sum(sum_); \
        aR##k = (r_ < nr) ? fast_rcp(sum_) : 0.f; }
        REP16(LOADK)
#undef LOADK
    }

    // zero-fill out rows 512..1023 for this (b, half) slice (overlaps compute)
    {
        const float4 z = make_float4(0.f, 0.f, 0.f, 0.f);
        float4* __restrict__ zb = reinterpret_cast<float4*>(
            out + ((size_t)b << 20) + ((size_t)(512 + (half << 6)) << 10));
        #pragma unroll 4
        for (int i = t; i < 64 * 256; i += 256) zb[i] = z;
    }

#define COL_PHASE(CSCUR)                                                      \
  do {                                                                        \
    float4 p0 = make_float4(0.f, 0.f, 0.f, 0.f), p1 = p0, p2 = p0, p3 = p0;   \
    REP16(COLK)                                                               \
    *reinterpret_cast<float4*>(cls + (w << 10) + c4)       = p0;              \
    *reinterpret_cast<float4*>(cls + (w << 10) + 256 + c4) = p1;              \
    *reinterpret_cast<float4*>(cls + (w << 10) + 512 + c4) = p2;              \
    *reinterpret_cast<float4*>(cls + (w << 10) + 768 + c4) = p3;              \
    __syncthreads();                                                          \
    {                                                                         \
      float* __restrict__ cur = (CSCUR) + (b << 10);                          \
      _Pragma("unroll")                                                       \
      for (int hh = 0; hh < 4; ++hh) {                                        \
        const int c = t + (hh << 8);                                          \
        const float v = cls[c] + cls[1024 + c] + cls[2048 + c] + cls[3072 + c]; \
        if (v != 0.f) atomicAdd(cur + c, v);                                  \
      }                                                                       \
    }                                                                         \
    __syncthreads();                                                          \
  } while (0)
#define COLK(k) col_acc(R##k, aR##k, p0, p1, p2, p3);

#define ROW_PHASE(CSPREV)                                                     \
  do {                                                                        \
    float4 wv0, wv1, wv2, wv3;                                                \
    load_wv((CSPREV) + (b << 10), c4, nc, wv0, wv1, wv2, wv3);                \
    REP16(ROWK)                                                               \
  } while (0)
#define ROWK(k) { \
    const float sum_ = wave_sum(row_dot(R##k, wv0, wv1, wv2, wv3)); \
    aR##k = (rbase + k < nr) ? fast_rcp(sum_) : 0.f; }

    COL_PHASE(cs0);  grid.sync();                               // epoch 0
    if (t < 128) cs2[(b << 10) + (half << 7) + t] = 0.f;        // for epoch 2
    ROW_PHASE(cs0);  COL_PHASE(cs1);  grid.sync();              // epoch 1
    if (t < 128) cs0[(b << 10) + (half << 7) + t] = 0.f;        // for epoch 3
    ROW_PHASE(cs1);  COL_PHASE(cs2);  grid.sync();              // epoch 2
    if (t < 128) cs1[(b << 10) + (half << 7) + t] = 0.f;        // for epoch 4
    ROW_PHASE(cs2);  COL_PHASE(cs0);  grid.sync();              // epoch 3
    ROW_PHASE(cs0);  COL_PHASE(cs1);  grid.sync();              // epoch 4

    // ---- output: out = E * a[r] * (1/cs1[c]) straight from registers ----
    {
        float4 wv0, wv1, wv2, wv3;
        load_wv(cs1 + (b << 10), c4, nc, wv0, wv1, wv2, wv3);
        float* __restrict__ ob = out + ((size_t)b << 20);
#define OUTK(k) out_row(R##k, aR##k, wv0, wv1, wv2, wv3, \
                        ob + ((size_t)(rbase + k) << 10), c4);
        REP16(OUTK)
#undef OUTK
    }
}

// ==================== round-7 fallback (coop launch failure) ===============

#define RCH 32

__device__ __forceinline__ void phase2_col(
    const __half* __restrict__ e_lds, const float* __restrict__ a_lds,
    int b, int nc, int t, float* __restrict__ cs_cur)
{
    const int c0 = t << 1;
    if (c0 >= nc) return;
    float s0 = 0.f, s1 = 0.f;
    #pragma unroll
    for (int rr = 0; rr < RCH; ++rr) {
        const float2 f = __half22float2(
            *reinterpret_cast<const __half2*>(e_lds + (rr << 10) + c0));
        const float av = a_lds[rr];
        s0 = fmaf(f.x, av, s0);
        s1 = fmaf(f.y, av, s1);
    }
    if (s0 != 0.f) atomicAdd(cs_cur + (b << 10) + c0, s0);
    if (s1 != 0.f) atomicAdd(cs_cur + (b << 10) + c0 + 1, s1);
}

__device__ __forceinline__ void decode_pair_bid(int bid, int& b, int& rc) {
    const int xcd = bid & 7;
    const int j = bid >> 3;
    rc = j & 15;
    b = (xcd << 3) | (j >> 4);
}

__global__ __launch_bounds__(512) void pair_first(
    const float* __restrict__ s, const int* __restrict__ nrows,
    const int* __restrict__ ncols, __half* __restrict__ E,
    float* __restrict__ a, float* __restrict__ cs_cur,
    float* __restrict__ cs_next)
{
    int b, rc;
    decode_pair_bid(blockIdx.x, b, rc);
    const int t = threadIdx.x;
    if (t < 64) cs_next[(b << 10) + (rc << 6) + t] = 0.f;

    const int nr = nrows[b];
    const int r0 = rc << 5;
    if (r0 >= nr) return;
    const int nc = ncols[b];

    __shared__ __half e_lds[RCH * 1024];
    __shared__ float a_lds[RCH];

    const int wave = t >> 6;
    const int lane = t & 63;
    const int cbase = lane << 4;
    const bool cOK = cbase < nc;

    #pragma unroll 1
    for (int k = 0; k < 4; ++k) {
        const int rr = (wave << 2) + k;
        const int r = r0 + rr;
        float sum = 0.f;
        __half2 h[8];
        if (r < nr && cOK) {
            const float* __restrict__ srow =
                s + ((size_t)b << 20) + ((size_t)r << 10) + cbase;
            float e[16];
            #pragma unroll
            for (int q = 0; q < 4; ++q) {
                const float4 x = *reinterpret_cast<const float4*>(srow + (q << 2));
                e[4*q+0] = __expf(x.x); e[4*q+1] = __expf(x.y);
                e[4*q+2] = __expf(x.z); e[4*q+3] = __expf(x.w);
            }
            #pragma unroll
            for (int j = 0; j < 16; ++j)
                if (cbase + j >= nc) e[j] = 0.f;
            #pragma unroll
            for (int q = 0; q < 8; ++q)
                h[q] = __floats2half2_rn(e[2*q], e[2*q+1]);
            __half* __restrict__ erow =
                E + ((size_t)b << 19) + ((size_t)r << 10) + cbase;
            *reinterpret_cast<float4*>(erow)     = *reinterpret_cast<const float4*>(&h[0]);
            *reinterpret_cast<float4*>(erow + 8) = *reinterpret_cast<const float4*>(&h[4]);
            #pragma unroll
            for (int j = 0; j < 16; ++j) sum += e[j];
        } else {
            #pragma unroll
            for (int q = 0; q < 8; ++q) h[q] = __floats2half2_rn(0.f, 0.f);
        }
        __half* dst = e_lds + (rr << 10) + cbase;
        *reinterpret_cast<float4*>(dst)     = *reinterpret_cast<const float4*>(&h[0]);
        *reinterpret_cast<float4*>(dst + 8) = *reinterpret_cast<const float4*>(&h[4]);
        sum = wave_sum(sum);
        if (lane == 0) a_lds[rr] = (r < nr) ? 1.0f / sum : 0.f;
    }
    __syncthreads();
    if (t < RCH) a[(b << 9) + r0 + t] = a_lds[t];

    phase2_col(e_lds, a_lds, b, nc, t, cs_cur);
}

__global__ __launch_bounds__(512) void pair_mid(
    const __half* __restrict__ E, const int* __restrict__ nrows,
    const int* __restrict__ ncols, const float* __restrict__ cs_prev,
    float* __restrict__ a, float* __restrict__ cs_cur,
    float* __restrict__ cs_next)
{
    int b, rc;
    decode_pair_bid(blockIdx.x, b, rc);
    const int t = threadIdx.x;
    if (t < 64) cs_next[(b << 10) + (rc << 6) + t] = 0.f;

    const int nr = nrows[b];
    const int r0 = rc << 5;
    if (r0 >= nr) return;
    const int nc = ncols[b];

    __shared__ __half e_lds[RCH * 1024];
    __shared__ float a_lds[RCH];

    const int wave = t >> 6;
    const int lane = t & 63;
    const int cbase = lane << 4;
    const bool cOK = cbase < nc;

    float wgt[16];
    if (cOK) {
        const float* __restrict__ csp = cs_prev + (b << 10) + cbase;
        #pragma unroll
        for (int q = 0; q < 4; ++q) {
            const float4 c4v = *reinterpret_cast<const float4*>(csp + (q << 2));
            wgt[4*q+0] = (cbase + 4*q + 0 < nc) ? fast_rcp(c4v.x) : 0.f;
            wgt[4*q+1] = (cbase + 4*q + 1 < nc) ? fast_rcp(c4v.y) : 0.f;
            wgt[4*q+2] = (cbase + 4*q + 2 < nc) ? fast_rcp(c4v.z) : 0.f;
            wgt[4*q+3] = (cbase + 4*q + 3 < nc) ? fast_rcp(c4v.w) : 0.f;
        }
    }

    #pragma unroll 1
    for (int k = 0; k < 4; ++k) {
        const int rr = (wave << 2) + k;
        const int r = r0 + rr;
        float s0 = 0.f, s1 = 0.f;
        float4 p0, p1;
        if (r < nr && cOK) {
            const __half* __restrict__ erow =
                E + ((size_t)b << 19) + ((size_t)r << 10) + cbase;
            p0 = *reinterpret_cast<const float4*>(erow);
            p1 = *reinterpret_cast<const float4*>(erow + 8);
            const __half2* h0 = reinterpret_cast<const __half2*>(&p0);
            const __half2* h1 = reinterpret_cast<const __half2*>(&p1);
            #pragma unroll
            for (int q = 0; q < 4; ++q) {
                const float2 f = __half22float2(h0[q]);
                s0 = fmaf(f.x, wgt[2*q], s0);
                s1 = fmaf(f.y, wgt[2*q+1], s1);
            }
            #pragma unroll
            for (int q = 0; q < 4; ++q) {
                const float2 f = __half22float2(h1[q]);
                s0 = fmaf(f.x, wgt[8+2*q], s0);
                s1 = fmaf(f.y, wgt[8+2*q+1], s1);
            }
        } else {
            p0 = make_float4(0.f, 0.f, 0.f, 0.f);
            p1 = p0;
        }
        __half* dst = e_lds + (rr << 10) + cbase;
        *reinterpret_cast<float4*>(dst)     = p0;
        *reinterpret_cast<float4*>(dst + 8) = p1;
        const float sum = wave_sum(s0 + s1);
        if (lane == 0) a_lds[rr] = (r < nr) ? 1.0f / sum : 0.f;
    }
    __syncthreads();
    if (t < RCH) a[(b << 9) + r0 + t] = a_lds[t];

    phase2_col(e_lds, a_lds, b, nc, t, cs_cur);
}

__global__ __launch_bounds__(256) void out_step_f(
    const __half* __restrict__ E, const int* __restrict__ nrows,
    const int* __restrict__ ncols, const float* __restrict__ a,
    const float* __restrict__ cs, float* __restrict__ out)
{
    const int bid = blockIdx.x;
    const int xcd = bid & 7;
    const int j = bid >> 3;
    const int r = j & 1023;
    const int b = (xcd << 3) | (j >> 10);
    const int c0 = threadIdx.x << 2;

    const int nr = nrows[b];
    const int nc = ncols[b];
    float4 o = make_float4(0.f, 0.f, 0.f, 0.f);
    if (r < nr && c0 < nc) {
        const float ar = a[(b << 9) + r];
        float2 pk = *reinterpret_cast<const float2*>(
            E + ((size_t)b << 19) + ((size_t)r << 10) + c0);
        const float2 f01 = __half22float2(reinterpret_cast<const __half2*>(&pk)[0]);
        const float2 f23 = __half22float2(reinterpret_cast<const __half2*>(&pk)[1]);
        const float4 c4v = *reinterpret_cast<const float4*>(cs + (b << 10) + c0);
        o.x = f01.x * ar * fast_rcp(c4v.x);
        o.y = (c0 + 1 < nc) ? f01.y * ar * fast_rcp(c4v.y) : 0.f;
        o.z = (c0 + 2 < nc) ? f23.x * ar * fast_rcp(c4v.z) : 0.f;
        o.w = (c0 + 3 < nc) ? f23.y * ar * fast_rcp(c4v.w) : 0.f;
    }
    *reinterpret_cast<float4*>(out + ((size_t)b << 20) + ((size_t)r << 10) + c0) = o;
}

// ============================================================================

extern "C" void kernel_launch(void* const* d_in, const int* in_sizes, int n_in,
                              void* d_out, int out_size, void* d_ws, size_t ws_size,
                              hipStream_t stream) {
    const float* s = (const float*)d_in[0];
    const int* nrows = (const int*)d_in[1];
    const int* ncols = (const int*)d_in[2];
    float* out = (float*)d_out;

    const size_t CS_ELEMS = (size_t)B_DIM * 1024;   // 65536

    // --- primary: cooperative single kernel (needs 768 KiB ws) ---
    bool coop_done = false;
    if (ws_size >= 3 * CS_ELEMS * sizeof(float)) {
        float* cs0 = (float*)d_ws;
        float* cs1 = cs0 + CS_ELEMS;
        float* cs2 = cs1 + CS_ELEMS;
        hipMemsetAsync(cs0, 0, CS_ELEMS * sizeof(float), stream);
        void* args[] = {(void*)&s, (void*)&nrows, (void*)&ncols,
                        (void*)&cs0, (void*)&cs1, (void*)&cs2, (void*)&out};
        hipError_t err = hipLaunchCooperativeKernel(
            reinterpret_cast<const void*>(sinkhorn_coop),
            dim3(512), dim3(256), args, 0, stream);
        coop_done = (err == hipSuccess);
        if (!coop_done) (void)hipGetLastError();   // clear sticky error
    }
    if (coop_done) return;

    // --- fallback: round-7 kernel sequence (needs ~65 MiB ws) ---
    const size_t E_BYTES = (size_t)B_DIM * 512 * 1024 * 2;
    {
        __half* E = (__half*)d_ws;
        float* a = (float*)((char*)d_ws + E_BYTES);
        float* cs0 = a + B_DIM * 512;
        float* cs1 = cs0 + CS_ELEMS;
        float* cs2 = cs1 + CS_ELEMS;

        hipMemsetAsync(cs0, 0, CS_ELEMS * sizeof(float), stream);

        const int nblk = 16 * B_DIM;
        pair_first<<<nblk, 512, 0, stream>>>(s, nrows, ncols, E, a, cs0, cs1);
        pair_mid<<<nblk, 512, 0, stream>>>(E, nrows, ncols, cs0, a, cs1, cs2);
        pair_mid<<<nblk, 512, 0, stream>>>(E, nrows, ncols, cs1, a, cs2, cs0);
        pair_mid<<<nblk, 512, 0, stream>>>(E, nrows, ncols, cs2, a, cs0, cs1);
        pair_mid<<<nblk, 512, 0, stream>>>(E, nrows, ncols, cs0, a, cs1, cs2);
        out_step_f<<<65536, 256, 0, stream>>>(E, nrows, ncols, a, cs1, out);
    }
}

// Round 11
// 183.057 us; speedup vs baseline: 3.1127x; 3.1127x over previous
//
#include <hip/hip_runtime.h>
#include <hip/hip_fp16.h>

// Sinkhorn (B=64, R=1024, C=1024, fp32, TAU=1, MAX_ITER=10), linear space.
// E[b][r][c] = exp(s) fp16, full 1024-col rows (zero for c >= nc) for valid
// rows r < nr; rows >= nr stay poison but are neutralized by a[r]=0.
//   a[r]  = 1 / SUM_c E[r,c] * w_prev[c]   (w = 1/cs_prev; first pair: w=1)
//   cs[c] = SUM_{r<nr} E[r,c] * a[r]       (split-K atomics, 32-row chunks)
// Block = (batch, 32-row chunk): grid 1024 (= 64 b x 16 chunks), 256 thr,
// XCD-octet decode (bid&7 -> batch group) so each XCD keeps its 8 batches'
// E slice (~3.9 MB) in its private L2 across phases.
//   phase 0: w_lds[1024] = masked rcp(cs_prev)      (once per block)
//   phase 1: 16 lanes/row, 4 rows/wave in parallel; 16 strided uint2 loads
//            + ds_read_b128 weights; 4-stage shfl_xor reduce -> a_lds/a
//   phase 2: thread = 4 cols x 32 rows (global, L2-hot), 4 atomicAdd
// cs0/1/2 rotate; kernel i zeroes cs_next (idle that dispatch).
// out = E * a[r] * rcp(cs_final[c]) on valid region, else 0.

#define B_DIM 64
#define CROWS 32

__device__ __forceinline__ float fast_rcp(float x) {
#if __has_builtin(__builtin_amdgcn_rcpf)
    return __builtin_amdgcn_rcpf(x);
#else
    return 1.0f / x;
#endif
}

__device__ __forceinline__ unsigned int pack2f(float a, float b) {
    const __half2 h = __floats2half2_rn(a, b);
    return __builtin_bit_cast(unsigned int, h);
}
__device__ __forceinline__ float2 unpack2f(unsigned int u) {
    return __half22float2(__builtin_bit_cast(__half2, u));
}

// bid&7 = XCD octet = b>>3 (assumes round-robin block->XCD dispatch).
__device__ __forceinline__ void decode_bid(int bid, int& b, int& rc) {
    const int xcd = bid & 7;
    const int j = bid >> 3;        // 0..127
    rc = j & 15;
    b = (xcd << 3) | (j >> 4);
}

// Phase 2: thread -> 4 cols x 32 rows; E re-read from global (L2-hot after
// phase 1 on the same XCD); a_lds broadcast; rows >= nr have av == 0 which
// neutralizes any poison E (finite fp16 -> +/-0 contributions).
__device__ __forceinline__ void col_atomic_phase(
    const __half* __restrict__ Eb, const float* __restrict__ a_lds,
    int r0, int nc, int t, float* __restrict__ cs_b)
{
    const int c0 = t << 2;
    if (c0 >= nc) return;
    float a0 = 0.f, a1 = 0.f, a2 = 0.f, a3 = 0.f;
    const __half* __restrict__ p = Eb + ((size_t)r0 << 10) + c0;
    #pragma unroll
    for (int rr = 0; rr < CROWS; ++rr) {
        const float av = a_lds[rr];
        const uint2 raw = *reinterpret_cast<const uint2*>(p + ((size_t)rr << 10));
        const float2 f01 = unpack2f(raw.x);
        const float2 f23 = unpack2f(raw.y);
        a0 = fmaf(f01.x, av, a0);
        a1 = fmaf(f01.y, av, a1);
        a2 = fmaf(f23.x, av, a2);
        a3 = fmaf(f23.y, av, a3);
    }
    if (a0 != 0.f) atomicAdd(cs_b + c0 + 0, a0);
    if (a1 != 0.f) atomicAdd(cs_b + c0 + 1, a1);
    if (a2 != 0.f) atomicAdd(cs_b + c0 + 2, a2);
    if (a3 != 0.f) atomicAdd(cs_b + c0 + 3, a3);
}

// Pair 0: s -> E (exp, masked, FULL rows incl. zero tails), row sums w=1,
// col atomics. Zeroes its cs_next slice.
__global__ __launch_bounds__(256, 4) void pack_v11(
    const float* __restrict__ s, const int* __restrict__ nrows,
    const int* __restrict__ ncols, __half* __restrict__ E,
    float* __restrict__ a, float* __restrict__ cs_cur,
    float* __restrict__ cs_next)
{
    int b, rc; decode_bid(blockIdx.x, b, rc);
    const int t = threadIdx.x;
    if (t < 64) cs_next[(b << 10) + (rc << 6) + t] = 0.f;
    const int nr = nrows[b];
    const int r0 = rc << 5;
    if (r0 >= nr) return;                 // uniform, before any barrier
    const int nc = ncols[b];

    __shared__ float a_lds[CROWS];

    const int w = t >> 6;
    const int l = t & 63;
    const int sub = l >> 4;               // 0..3: row within wave-quad
    const int j16 = (l & 15) << 2;        // col offset within each 64-block
    __half* __restrict__ Eb = E + ((size_t)b << 19);
    const float* __restrict__ sb = s + ((size_t)b << 20);

    #pragma unroll
    for (int q = 0; q < 2; ++q) {
        const int rr = (q << 4) + (w << 2) + sub;   // 0..31
        const int r = r0 + rr;
        float acc = 0.f;
        if (r < nr) {
            const float* __restrict__ srow = sb + ((size_t)r << 10);
            __half* __restrict__ erow = Eb + ((size_t)r << 10);
            #pragma unroll
            for (int k = 0; k < 16; ++k) {
                const int c = (k << 6) + j16;
                float e0 = 0.f, e1 = 0.f, e2 = 0.f, e3 = 0.f;
                if (c < nc) {
                    const float4 x = *reinterpret_cast<const float4*>(srow + c);
                    e0 = __expf(x.x);
                    e1 = (c + 1 < nc) ? __expf(x.y) : 0.f;
                    e2 = (c + 2 < nc) ? __expf(x.z) : 0.f;
                    e3 = (c + 3 < nc) ? __expf(x.w) : 0.f;
                }
                uint2 pk;
                pk.x = pack2f(e0, e1);
                pk.y = pack2f(e2, e3);
                *reinterpret_cast<uint2*>(erow + c) = pk;   // full row (zero tails)
                acc += (e0 + e1) + (e2 + e3);
            }
        }
        // 4-stage reduce within each 16-lane group
        acc += __shfl_xor(acc, 1);
        acc += __shfl_xor(acc, 2);
        acc += __shfl_xor(acc, 4);
        acc += __shfl_xor(acc, 8);
        if ((l & 15) == 0) {
            const float av = (r < nr) ? fast_rcp(acc) : 0.f;
            a_lds[rr] = av;
            a[(b << 9) + r] = av;
        }
    }
    __syncthreads();

    col_atomic_phase(Eb, a_lds, r0, nc, t, cs_cur + (b << 10));
}

// Pairs 1..4: w = 1/cs_prev (block-shared), row dots from E, col atomics.
__global__ __launch_bounds__(256, 4) void mid_v11(
    const __half* __restrict__ E, const int* __restrict__ nrows,
    const int* __restrict__ ncols, const float* __restrict__ cs_prev,
    float* __restrict__ a, float* __restrict__ cs_cur,
    float* __restrict__ cs_next)
{
    int b, rc; decode_bid(blockIdx.x, b, rc);
    const int t = threadIdx.x;
    if (t < 64) cs_next[(b << 10) + (rc << 6) + t] = 0.f;
    const int nr = nrows[b];
    const int r0 = rc << 5;
    if (r0 >= nr) return;
    const int nc = ncols[b];

    __shared__ float w_lds[1024];
    __shared__ float a_lds[CROWS];

    // phase 0: column weights, once per block
    {
        const int c0 = t << 2;
        const float4 v = *reinterpret_cast<const float4*>(cs_prev + (b << 10) + c0);
        float4 wv;
        wv.x = (c0 + 0 < nc) ? fast_rcp(v.x) : 0.f;
        wv.y = (c0 + 1 < nc) ? fast_rcp(v.y) : 0.f;
        wv.z = (c0 + 2 < nc) ? fast_rcp(v.z) : 0.f;
        wv.w = (c0 + 3 < nc) ? fast_rcp(v.w) : 0.f;
        *reinterpret_cast<float4*>(w_lds + c0) = wv;
    }
    __syncthreads();

    const int w = t >> 6;
    const int l = t & 63;
    const int sub = l >> 4;
    const int j16 = (l & 15) << 2;
    const __half* __restrict__ Eb = E + ((size_t)b << 19);

    #pragma unroll
    for (int q = 0; q < 2; ++q) {
        const int rr = (q << 4) + (w << 2) + sub;
        const int r = r0 + rr;
        float acc = 0.f;
        if (r < nr) {
            const __half* __restrict__ erow = Eb + ((size_t)r << 10);
            #pragma unroll
            for (int k = 0; k < 16; ++k) {
                const int c = (k << 6) + j16;
                const uint2 raw = *reinterpret_cast<const uint2*>(erow + c);
                const float4 wv = *reinterpret_cast<const float4*>(w_lds + c);
                const float2 f01 = unpack2f(raw.x);
                const float2 f23 = unpack2f(raw.y);
                acc = fmaf(f01.x, wv.x, acc);
                acc = fmaf(f01.y, wv.y, acc);
                acc = fmaf(f23.x, wv.z, acc);
                acc = fmaf(f23.y, wv.w, acc);
            }
        }
        acc += __shfl_xor(acc, 1);
        acc += __shfl_xor(acc, 2);
        acc += __shfl_xor(acc, 4);
        acc += __shfl_xor(acc, 8);
        if ((l & 15) == 0) {
            const float av = (r < nr) ? fast_rcp(acc) : 0.f;
            a_lds[rr] = av;
            a[(b << 9) + r] = av;
        }
    }
    __syncthreads();

    col_atomic_phase(Eb, a_lds, r0, nc, t, cs_cur + (b << 10));
}

// grid 65536 x 256. Block = one output row (b, r), XCD-partitioned.
__global__ __launch_bounds__(256) void out_step_f(
    const __half* __restrict__ E, const int* __restrict__ nrows,
    const int* __restrict__ ncols, const float* __restrict__ a,
    const float* __restrict__ cs, float* __restrict__ out)
{
    const int bid = blockIdx.x;
    const int xcd = bid & 7;
    const int j = bid >> 3;               // 0..8191
    const int r = j & 1023;
    const int b = (xcd << 3) | (j >> 10);
    const int c0 = threadIdx.x << 2;

    const int nr = nrows[b];
    const int nc = ncols[b];
    float4 o = make_float4(0.f, 0.f, 0.f, 0.f);
    if (r < nr && c0 < nc) {
        const float ar = a[(b << 9) + r];
        const uint2 raw = *reinterpret_cast<const uint2*>(
            E + ((size_t)b << 19) + ((size_t)r << 10) + c0);
        const float2 f01 = unpack2f(raw.x);
        const float2 f23 = unpack2f(raw.y);
        const float4 c4v = *reinterpret_cast<const float4*>(cs + (b << 10) + c0);
        o.x = f01.x * ar * fast_rcp(c4v.x);
        o.y = (c0 + 1 < nc) ? f01.y * ar * fast_rcp(c4v.y) : 0.f;
        o.z = (c0 + 2 < nc) ? f23.x * ar * fast_rcp(c4v.z) : 0.f;
        o.w = (c0 + 3 < nc) ? f23.y * ar * fast_rcp(c4v.w) : 0.f;
    }
    *reinterpret_cast<float4*>(out + ((size_t)b << 20) + ((size_t)r << 10) + c0) = o;
}

// ============================================================================

extern "C" void kernel_launch(void* const* d_in, const int* in_sizes, int n_in,
                              void* d_out, int out_size, void* d_ws, size_t ws_size,
                              hipStream_t stream) {
    const float* s = (const float*)d_in[0];
    const int* nrows = (const int*)d_in[1];
    const int* ncols = (const int*)d_in[2];
    float* out = (float*)d_out;

    // ws: E [64][512][1024] fp16 (64 MiB) | a [64][512] | cs0/1/2 [64][1024]
    const size_t E_BYTES = (size_t)B_DIM * 512 * 1024 * 2;
    const size_t CS_ELEMS = (size_t)B_DIM * 1024;
    __half* E = (__half*)d_ws;
    float* a = (float*)((char*)d_ws + E_BYTES);
    float* cs0 = a + (size_t)B_DIM * 512;
    float* cs1 = cs0 + CS_ELEMS;
    float* cs2 = cs1 + CS_ELEMS;

    hipMemsetAsync(cs0, 0, CS_ELEMS * sizeof(float), stream);

    const int nblk = 16 * B_DIM;   // 1024 blocks, XCD-octet decode in-kernel
    pack_v11<<<nblk, 256, 0, stream>>>(s, nrows, ncols, E, a, cs0, cs1);
    mid_v11<<<nblk, 256, 0, stream>>>(E, nrows, ncols, cs0, a, cs1, cs2);
    mid_v11<<<nblk, 256, 0, stream>>>(E, nrows, ncols, cs1, a, cs2, cs0);
    mid_v11<<<nblk, 256, 0, stream>>>(E, nrows, ncols, cs2, a, cs0, cs1);
    mid_v11<<<nblk, 256, 0, stream>>>(E, nrows, ncols, cs0, a, cs1, cs2);
    out_step_f<<<65536, 256, 0, stream>>>(E, nrows, ncols, a, cs1, out);
}

// Round 12
// 161.948 us; speedup vs baseline: 3.5184x; 1.1303x over previous
//
#include <hip/hip_runtime.h>
#include <hip/hip_fp16.h>

// Sinkhorn (B=64, R=1024, C=1024, fp32, TAU=1, MAX_ITER=10), linear space,
// fused row+col pairs (round-6 structure, phase-1 MLP fix).
// E[b][r][c] = exp(s) cached fp16 (512 row slots), zeroed for c >= nc within
// written granules; unwritten granules/rows hold finite poison neutralized by
// zero weights (w[c>=nc]=0) and a[r>=nr]=0 (fma(x,0,acc)==acc; fp16 poison
// 0xAAAA is a normal finite value).
//   a[r]  = 1 / SUM_c E[r,c] * w_prev[c]   (w_prev = 1/cs_prev, iter0: w=1)
//   cs[c] = SUM_{r<nr} E[r,c] * a[r]       (per-block LDS partials + atomics)
// Kernel per pair: block = (batch, 32-row chunk), grid (16,64), 512 thr.
//   phase 1: 8 waves x 4 rows; ALL 8 E-loads (2 float4/row) issued branch-
//            free before any math -> 8 loads in flight (was 2 with the
//            serial row loop); 4 independent shfl-reduce chains.
//   phase 2: thread = 8 cols (dwordx4) x 8 rows; LDS [4][1024] partials,
//            stride-1 reduce, <=2 global atomicAdd per thread.
// cs: 3 rotating buffers; kernel i zeroes cs_next for kernel i+1 (idle then).
// out = E * a[r] * rcp(cs_final[c]) on valid region, else 0.

#define B_DIM 64
#define RCH 32
#define NCH 16

__device__ __forceinline__ float fast_rcp(float x) {
#if __has_builtin(__builtin_amdgcn_rcpf)
    return __builtin_amdgcn_rcpf(x);
#else
    return 1.0f / x;
#endif
}

__device__ __forceinline__ float wave_sum(float x) {
    #pragma unroll
    for (int off = 1; off < 64; off <<= 1) x += __shfl_xor(x, off);
    return x;
}

__device__ __forceinline__ float2 unpack2f(unsigned int u) {
    return __half22float2(__builtin_bit_cast(__half2, u));
}

// 16-col dot: A,B = 16 packed fp16 (2 float4), weights as 4 named float4.
// Value-only unpacking (no address-taking -> no SROA/scratch demotion).
__device__ __forceinline__ float dot16(
    const float4 A, const float4 B, const float4 w0, const float4 w1,
    const float4 w2, const float4 w3)
{
    float2 f; float s0, s1;
    f = unpack2f(__builtin_bit_cast(unsigned int, A.x)); s0 = f.x * w0.x;          s1 = f.y * w0.y;
    f = unpack2f(__builtin_bit_cast(unsigned int, A.y)); s0 = fmaf(f.x, w0.z, s0); s1 = fmaf(f.y, w0.w, s1);
    f = unpack2f(__builtin_bit_cast(unsigned int, A.z)); s0 = fmaf(f.x, w1.x, s0); s1 = fmaf(f.y, w1.y, s1);
    f = unpack2f(__builtin_bit_cast(unsigned int, A.w)); s0 = fmaf(f.x, w1.z, s0); s1 = fmaf(f.y, w1.w, s1);
    f = unpack2f(__builtin_bit_cast(unsigned int, B.x)); s0 = fmaf(f.x, w2.x, s0); s1 = fmaf(f.y, w2.y, s1);
    f = unpack2f(__builtin_bit_cast(unsigned int, B.y)); s0 = fmaf(f.x, w2.z, s0); s1 = fmaf(f.y, w2.w, s1);
    f = unpack2f(__builtin_bit_cast(unsigned int, B.z)); s0 = fmaf(f.x, w3.x, s0); s1 = fmaf(f.y, w3.y, s1);
    f = unpack2f(__builtin_bit_cast(unsigned int, B.w)); s0 = fmaf(f.x, w3.z, s0); s1 = fmaf(f.y, w3.w, s1);
    return s0 + s1;
}

// Phase 2 (round-6 verbatim): col partial sums for this 32-row chunk.
// a_lds[j] == 0 for rows >= nr kills poison-E rows.
__device__ __forceinline__ void phase2_col(
    const __half* __restrict__ E, const float* __restrict__ a_lds,
    float* __restrict__ cls,   // [4][1024] LDS
    int b, int r0, int nr, int nc, int t, float* __restrict__ cs_cur)
{
    const int c0 = (t & 127) << 3;
    const int rsub = t >> 7;                 // 0..3
    float acc0 = 0.f, acc1 = 0.f, acc2 = 0.f, acc3 = 0.f;
    float acc4 = 0.f, acc5 = 0.f, acc6 = 0.f, acc7 = 0.f;
    if (c0 < nc) {
        const int rs = r0 + (rsub << 3);
        const __half* __restrict__ Eb = E + ((size_t)b << 19) + c0;
        #pragma unroll
        for (int k = 0; k < 8; ++k) {
            const int r = rs + k;
            const float4 p = *reinterpret_cast<const float4*>(Eb + ((size_t)r << 10));
            const float av = a_lds[r - r0];      // 0 for r >= nr
            const float2 f0 = unpack2f(__builtin_bit_cast(unsigned int, p.x));
            const float2 f1 = unpack2f(__builtin_bit_cast(unsigned int, p.y));
            const float2 f2 = unpack2f(__builtin_bit_cast(unsigned int, p.z));
            const float2 f3 = unpack2f(__builtin_bit_cast(unsigned int, p.w));
            acc0 = fmaf(f0.x, av, acc0); acc1 = fmaf(f0.y, av, acc1);
            acc2 = fmaf(f1.x, av, acc2); acc3 = fmaf(f1.y, av, acc3);
            acc4 = fmaf(f2.x, av, acc4); acc5 = fmaf(f2.y, av, acc5);
            acc6 = fmaf(f3.x, av, acc6); acc7 = fmaf(f3.y, av, acc7);
        }
    }
    float* dst = cls + (rsub << 10) + c0;
    *reinterpret_cast<float4*>(dst)     = make_float4(acc0, acc1, acc2, acc3);
    *reinterpret_cast<float4*>(dst + 4) = make_float4(acc4, acc5, acc6, acc7);
    __syncthreads();
    #pragma unroll
    for (int k = 0; k < 2; ++k) {
        const int c = t + (k << 9);
        const float v = cls[c] + cls[1024 + c] + cls[2048 + c] + cls[3072 + c];
        if (v != 0.f) atomicAdd(cs_cur + (b << 10) + c, v);
    }
}

// Pair 0 (round-6 verbatim): reads s fp32, writes E = exp(s) (zero-masked
// within written granules), row sums with w=1, then col phase.
__global__ __launch_bounds__(512) void pair_first(
    const float* __restrict__ s, const int* __restrict__ nrows,
    const int* __restrict__ ncols, __half* __restrict__ E,
    float* __restrict__ a, float* __restrict__ cs_cur,
    float* __restrict__ cs_next)
{
    const int b = blockIdx.y;
    const int rc = blockIdx.x;
    const int t = threadIdx.x;
    if (t < 64) cs_next[(b << 10) + (rc << 6) + t] = 0.f;

    const int nr = nrows[b];
    const int r0 = rc << 5;
    if (r0 >= nr) return;                 // uniform, before any barrier
    const int nc = ncols[b];

    __shared__ float a_lds[RCH];
    __shared__ float cls[4 * 1024];

    const int wave = t >> 6;
    const int lane = t & 63;
    const int cbase = lane << 4;          // 16 cols per lane
    const bool cOK = cbase < nc;

    #pragma unroll 1
    for (int k = 0; k < 4; ++k) {
        const int r = r0 + (wave << 2) + k;
        float sum = 0.f;
        if (r < nr && cOK) {
            const float* __restrict__ srow =
                s + ((size_t)b << 20) + ((size_t)r << 10) + cbase;
            __half* __restrict__ erow =
                E + ((size_t)b << 19) + ((size_t)r << 10) + cbase;
            float e[16];
            #pragma unroll
            for (int q = 0; q < 4; ++q) {
                const float4 x = *reinterpret_cast<const float4*>(srow + (q << 2));
                e[4 * q + 0] = __expf(x.x); e[4 * q + 1] = __expf(x.y);
                e[4 * q + 2] = __expf(x.z); e[4 * q + 3] = __expf(x.w);
            }
            #pragma unroll
            for (int j = 0; j < 16; ++j)
                if (cbase + j >= nc) e[j] = 0.f;
            __half2 h[8];
            #pragma unroll
            for (int q = 0; q < 8; ++q)
                h[q] = __floats2half2_rn(e[2 * q], e[2 * q + 1]);
            *reinterpret_cast<float4*>(erow)     = *reinterpret_cast<const float4*>(&h[0]);
            *reinterpret_cast<float4*>(erow + 8) = *reinterpret_cast<const float4*>(&h[4]);
            #pragma unroll
            for (int j = 0; j < 16; ++j) sum += e[j];
        }
        sum = wave_sum(sum);
        if (lane == 0) a_lds[(wave << 2) + k] = (r < nr) ? 1.0f / sum : 0.f;
    }
    __syncthreads();
    if (t < RCH) a[(b << 9) + r0 + t] = a_lds[t];

    phase2_col(E, a_lds, cls, b, r0, nr, nc, t, cs_cur);
}

// Pairs 1..4: phase 1 rebuilt for MLP — 8 branch-free E loads issued before
// any math; 4 independent dot+reduce chains. Phase 2 unchanged.
__global__ __launch_bounds__(512) void pair_mid(
    const __half* __restrict__ E, const int* __restrict__ nrows,
    const int* __restrict__ ncols, const float* __restrict__ cs_prev,
    float* __restrict__ a, float* __restrict__ cs_cur,
    float* __restrict__ cs_next)
{
    const int b = blockIdx.y;
    const int rc = blockIdx.x;
    const int t = threadIdx.x;
    if (t < 64) cs_next[(b << 10) + (rc << 6) + t] = 0.f;

    const int nr = nrows[b];
    const int r0 = rc << 5;
    if (r0 >= nr) return;
    const int nc = ncols[b];

    __shared__ float a_lds[RCH];
    __shared__ float cls[4 * 1024];

    const int wave = t >> 6;
    const int lane = t & 63;
    const int cbase = lane << 4;

    // masked column weights (4 named float4s; cs[c>=nc]==0 -> guarded)
    float4 w0, w1, w2, w3;
    {
        const float* __restrict__ csp = cs_prev + (b << 10) + cbase;
        const float4 v0 = *reinterpret_cast<const float4*>(csp);
        const float4 v1 = *reinterpret_cast<const float4*>(csp + 4);
        const float4 v2 = *reinterpret_cast<const float4*>(csp + 8);
        const float4 v3 = *reinterpret_cast<const float4*>(csp + 12);
        w0.x = (cbase +  0 < nc) ? fast_rcp(v0.x) : 0.f;
        w0.y = (cbase +  1 < nc) ? fast_rcp(v0.y) : 0.f;
        w0.z = (cbase +  2 < nc) ? fast_rcp(v0.z) : 0.f;
        w0.w = (cbase +  3 < nc) ? fast_rcp(v0.w) : 0.f;
        w1.x = (cbase +  4 < nc) ? fast_rcp(v1.x) : 0.f;
        w1.y = (cbase +  5 < nc) ? fast_rcp(v1.y) : 0.f;
        w1.z = (cbase +  6 < nc) ? fast_rcp(v1.z) : 0.f;
        w1.w = (cbase +  7 < nc) ? fast_rcp(v1.w) : 0.f;
        w2.x = (cbase +  8 < nc) ? fast_rcp(v2.x) : 0.f;
        w2.y = (cbase +  9 < nc) ? fast_rcp(v2.y) : 0.f;
        w2.z = (cbase + 10 < nc) ? fast_rcp(v2.z) : 0.f;
        w2.w = (cbase + 11 < nc) ? fast_rcp(v2.w) : 0.f;
        w3.x = (cbase + 12 < nc) ? fast_rcp(v3.x) : 0.f;
        w3.y = (cbase + 13 < nc) ? fast_rcp(v3.y) : 0.f;
        w3.z = (cbase + 14 < nc) ? fast_rcp(v3.z) : 0.f;
        w3.w = (cbase + 15 < nc) ? fast_rcp(v3.w) : 0.f;
    }

    // phase 1: rows rA..rA+3; ALL loads first (branch-free, always in-bounds:
    // r <= r0+31 <= 511 and E has 512 row slots; poison rows/cols neutralized
    // by w==0 and the (r<nr) mask below).
    {
        const int rA = r0 + (wave << 2);
        const __half* __restrict__ Eb = E + ((size_t)b << 19) + cbase;
        const __half* __restrict__ e0 = Eb + ((size_t)(rA + 0) << 10);
        const __half* __restrict__ e1 = Eb + ((size_t)(rA + 1) << 10);
        const __half* __restrict__ e2 = Eb + ((size_t)(rA + 2) << 10);
        const __half* __restrict__ e3 = Eb + ((size_t)(rA + 3) << 10);
        const float4 A0 = *reinterpret_cast<const float4*>(e0);
        const float4 B0 = *reinterpret_cast<const float4*>(e0 + 8);
        const float4 A1 = *reinterpret_cast<const float4*>(e1);
        const float4 B1 = *reinterpret_cast<const float4*>(e1 + 8);
        const float4 A2 = *reinterpret_cast<const float4*>(e2);
        const float4 B2 = *reinterpret_cast<const float4*>(e2 + 8);
        const float4 A3 = *reinterpret_cast<const float4*>(e3);
        const float4 B3 = *reinterpret_cast<const float4*>(e3 + 8);

        float d0 = dot16(A0, B0, w0, w1, w2, w3);
        float d1 = dot16(A1, B1, w0, w1, w2, w3);
        float d2 = dot16(A2, B2, w0, w1, w2, w3);
        float d3 = dot16(A3, B3, w0, w1, w2, w3);
        d0 = wave_sum(d0);
        d1 = wave_sum(d1);
        d2 = wave_sum(d2);
        d3 = wave_sum(d3);
        if (lane == 0) {
            const int rr = wave << 2;
            a_lds[rr + 0] = (rA + 0 < nr) ? fast_rcp(d0) : 0.f;
            a_lds[rr + 1] = (rA + 1 < nr) ? fast_rcp(d1) : 0.f;
            a_lds[rr + 2] = (rA + 2 < nr) ? fast_rcp(d2) : 0.f;
            a_lds[rr + 3] = (rA + 3 < nr) ? fast_rcp(d3) : 0.f;
        }
    }
    __syncthreads();
    if (t < RCH) a[(b << 9) + r0 + t] = a_lds[t];

    phase2_col(E, a_lds, cls, b, r0, nr, nc, t, cs_cur);
}

// grid (65536), block 256. One float4 of output per thread (round-6 verbatim).
__global__ __launch_bounds__(256) void out_step_f(
    const __half* __restrict__ E, const int* __restrict__ nrows,
    const int* __restrict__ ncols, const float* __restrict__ a,
    const float* __restrict__ cs, float* __restrict__ out)
{
    const int g = (blockIdx.x << 8) + threadIdx.x;  // 0..16777215
    const int b = g >> 18;
    const int rem = g & 262143;
    const int r = rem >> 8;
    const int c0 = (rem & 255) << 2;
    const int nr = nrows[b];
    const int nc = ncols[b];
    float4 o = make_float4(0.f, 0.f, 0.f, 0.f);
    if (r < nr && c0 < nc) {
        const float ar = a[(b << 9) + r];
        const uint2 raw = *reinterpret_cast<const uint2*>(
            E + ((size_t)b << 19) + ((size_t)r << 10) + c0);
        const float2 f01 = unpack2f(raw.x);
        const float2 f23 = unpack2f(raw.y);
        const float4 c4 = *reinterpret_cast<const float4*>(cs + (b << 10) + c0);
        o.x = f01.x * ar * fast_rcp(c4.x);
        o.y = (c0 + 1 < nc) ? f01.y * ar * fast_rcp(c4.y) : 0.f;
        o.z = (c0 + 2 < nc) ? f23.x * ar * fast_rcp(c4.z) : 0.f;
        o.w = (c0 + 3 < nc) ? f23.y * ar * fast_rcp(c4.w) : 0.f;
    }
    reinterpret_cast<float4*>(out)[g] = o;
}

// ============================================================================

extern "C" void kernel_launch(void* const* d_in, const int* in_sizes, int n_in,
                              void* d_out, int out_size, void* d_ws, size_t ws_size,
                              hipStream_t stream) {
    const float* s = (const float*)d_in[0];
    const int* nrows = (const int*)d_in[1];
    const int* ncols = (const int*)d_in[2];
    float* out = (float*)d_out;

    // ws: E [64][512][1024] fp16 (64 MiB) | a [64][512] | cs0/1/2 [64][1024]
    const size_t E_BYTES = (size_t)B_DIM * 512 * 1024 * 2;
    const size_t CS_ELEMS = (size_t)B_DIM * 1024;
    __half* E = (__half*)d_ws;
    float* a = (float*)((char*)d_ws + E_BYTES);
    float* cs0 = a + (size_t)B_DIM * 512;
    float* cs1 = cs0 + CS_ELEMS;
    float* cs2 = cs1 + CS_ELEMS;

    hipMemsetAsync(cs0, 0, CS_ELEMS * sizeof(float), stream);

    const dim3 grid(NCH, B_DIM);
    // pair i: prev=cs[(i+2)%3], cur=cs[i%3], next=cs[(i+1)%3]
    pair_first<<<grid, 512, 0, stream>>>(s, nrows, ncols, E, a, cs0, cs1);
    pair_mid<<<grid, 512, 0, stream>>>(E, nrows, ncols, cs0, a, cs1, cs2);
    pair_mid<<<grid, 512, 0, stream>>>(E, nrows, ncols, cs1, a, cs2, cs0);
    pair_mid<<<grid, 512, 0, stream>>>(E, nrows, ncols, cs2, a, cs0, cs1);
    pair_mid<<<grid, 512, 0, stream>>>(E, nrows, ncols, cs0, a, cs1, cs2);
    out_step_f<<<65536, 256, 0, stream>>>(E, nrows, ncols, a, cs1, out);
}